// Round 4
// baseline (924.576 us; speedup 1.0000x reference)
//
#include <hip/hip_runtime.h>
#include <math.h>

#define NJ 16
#define NV 778
#define M3 2334   // NV*3
#define S  8      // samples per block in k3

typedef float f32x8  __attribute__((ext_vector_type(8)));
typedef float f32x16 __attribute__((ext_vector_type(16)));

__device__ __forceinline__ f32x8 splat8(float x) {
    f32x8 r = {x, x, x, x, x, x, x, x};
    return r;
}
// elementwise fused r = f*s + c  (all constant indices -> pure SSA)
__device__ __forceinline__ f32x8 fma8v(f32x8 f, float s, f32x8 c) {
    f32x8 r;
    r[0] = fmaf(f[0], s, c[0]); r[1] = fmaf(f[1], s, c[1]);
    r[2] = fmaf(f[2], s, c[2]); r[3] = fmaf(f[3], s, c[3]);
    r[4] = fmaf(f[4], s, c[4]); r[5] = fmaf(f[5], s, c[5]);
    r[6] = fmaf(f[6], s, c[6]); r[7] = fmaf(f[7], s, c[7]);
    return r;
}

// d_out layout (floats): verts [N*2334] | joints [N*48] | Rs [N*144]
// Scratch stashing (no d_ws needed):
//   SJ/JT (528 floats)  -> joints region (overwritten by k4 at the end)
//   A (N x 16 x 12)     -> verts region, first 192 floats of each sample row

// ---------------- K0: SJ[b,j,c] = sum_v shapedirs[b,v,c]*Jreg[v,j]; JT = vtemp row
__global__ __launch_bounds__(64) void k0_prep(
    const float* __restrict__ shapedirs,
    const float* __restrict__ Jreg,
    const float* __restrict__ vtemp,
    float* __restrict__ SJJT)   // 528 floats
{
    int b = blockIdx.x / 16;    // 0..9 = shapedirs row, 10 = vtemp
    int j = blockIdx.x % 16;
    int t = threadIdx.x;
    const float* src = (b < 10) ? (shapedirs + (size_t)b * M3) : vtemp;
    float a0 = 0.f, a1 = 0.f, a2 = 0.f;
    for (int v = t; v < NV; v += 64) {
        float jr = Jreg[v * 16 + j];
        a0 = fmaf(src[v*3 + 0], jr, a0);
        a1 = fmaf(src[v*3 + 1], jr, a1);
        a2 = fmaf(src[v*3 + 2], jr, a2);
    }
#pragma unroll
    for (int m = 1; m < 64; m <<= 1) {
        a0 += __shfl_xor(a0, m);
        a1 += __shfl_xor(a1, m);
        a2 += __shfl_xor(a2, m);
    }
    if (t == 0) {
        int base = (b < 10) ? (b*48 + j*3) : (480 + j*3);
        SJJT[base + 0] = a0;
        SJJT[base + 1] = a1;
        SJJT[base + 2] = a2;
    }
}

// ---------------- K1: Rodrigues, one thread per (n, joint)
__global__ __launch_bounds__(256) void k1_rodrigues(
    const float* __restrict__ theta, float* __restrict__ RsOut, int N)
{
    int idx = blockIdx.x * 256 + threadIdx.x;
    if (idx >= N * NJ) return;
    int n = idx >> 4;
    int j = idx & 15;
    float t0 = theta[n*48 + j*3 + 0];
    float t1 = theta[n*48 + j*3 + 1];
    float t2 = theta[n*48 + j*3 + 2];
    const float eps = 1e-8f;
    float a0 = t0 + eps, a1 = t1 + eps, a2 = t2 + eps;
    float angle = sqrtf(a0*a0 + a1*a1 + a2*a2);
    float inv  = 1.0f / angle;
    float half = 0.5f * angle;
    float sh = sinf(half), chh = cosf(half);
    float qw = chh;
    float qx = sh * t0 * inv;
    float qy = sh * t1 * inv;
    float qz = sh * t2 * inv;
    float qn = 1.0f / sqrtf(qw*qw + qx*qx + qy*qy + qz*qz);
    qw *= qn; qx *= qn; qy *= qn; qz *= qn;
    float w2=qw*qw, x2=qx*qx, y2=qy*qy, z2=qz*qz;
    float wx=qw*qx, wy=qw*qy, wz=qw*qz;
    float xy=qx*qy, xz=qx*qz, yz=qy*qz;
    float* R = RsOut + (size_t)idx * 9;
    R[0] = w2 + x2 - y2 - z2;
    R[1] = 2.f*(xy - wz);
    R[2] = 2.f*(wy + xz);
    R[3] = 2.f*(wz + xy);
    R[4] = w2 - x2 + y2 - z2;
    R[5] = 2.f*(yz - wx);
    R[6] = 2.f*(xz - wy);
    R[7] = 2.f*(wx + yz);
    R[8] = w2 - x2 - y2 + z2;
}

// ---------------- K2: kinematic chain, one thread per (n, chain). 5 chains of 3 joints.
__global__ __launch_bounds__(64) void k2_chain(
    const float* __restrict__ beta,
    const float* __restrict__ Rs,     // d_out Rs region
    const float* __restrict__ SJJT,   // 528 floats
    float* __restrict__ Abuf,         // verts region; A[n] at n*M3, 192 floats
    int N)
{
    __shared__ float sS[528];
    for (int i = threadIdx.x; i < 528; i += 64) sS[i] = SJJT[i];
    __syncthreads();
    int gid = blockIdx.x * 64 + threadIdx.x;
    if (gid >= N * 5) return;
    int n  = gid / 5;
    int ch = gid % 5;

    float b[10];
#pragma unroll
    for (int i = 0; i < 10; ++i) b[i] = beta[n*10 + i];

    int jidx[4];
    jidx[0] = 0; jidx[1] = ch*3 + 1; jidx[2] = ch*3 + 2; jidx[3] = ch*3 + 3;
    float J[4][3];
#pragma unroll
    for (int q = 0; q < 4; ++q) {
        int j = jidx[q];
#pragma unroll
        for (int c = 0; c < 3; ++c) {
            float acc = sS[480 + j*3 + c];
#pragma unroll
            for (int qq = 0; qq < 10; ++qq)
                acc = fmaf(b[qq], sS[qq*48 + j*3 + c], acc);
            J[q][c] = acc;
        }
    }

    const float* Rn = Rs + (size_t)n * 144;
    float* An = Abuf + (size_t)n * M3;

    float GpR[9], Gpt[3];
#pragma unroll
    for (int r = 0; r < 3; ++r) {
        GpR[r*3+0] =  Rn[r*3+0];
        GpR[r*3+1] = -Rn[r*3+1];
        GpR[r*3+2] = -Rn[r*3+2];
    }
    Gpt[0] = J[0][0]; Gpt[1] = J[0][1]; Gpt[2] = J[0][2];

    if (ch == 0) {
#pragma unroll
        for (int r = 0; r < 3; ++r) {
            float rel = GpR[r*3+0]*J[0][0] + GpR[r*3+1]*J[0][1] + GpR[r*3+2]*J[0][2];
            An[r*4 + 0] = GpR[r*3+0];
            An[r*4 + 1] = GpR[r*3+1];
            An[r*4 + 2] = GpR[r*3+2];
            An[r*4 + 3] = Gpt[r] - rel;
        }
    }

#pragma unroll
    for (int st = 0; st < 3; ++st) {
        int i = jidx[st+1];
        const float* Ri = Rn + (size_t)i * 9;
        float t0 = J[st+1][0] - J[st][0];
        float t1 = J[st+1][1] - J[st][1];
        float t2 = J[st+1][2] - J[st][2];
        float GR[9], Gt[3];
#pragma unroll
        for (int r = 0; r < 3; ++r) {
#pragma unroll
            for (int c = 0; c < 3; ++c)
                GR[r*3+c] = GpR[r*3+0]*Ri[c] + GpR[r*3+1]*Ri[3+c] + GpR[r*3+2]*Ri[6+c];
            Gt[r] = GpR[r*3+0]*t0 + GpR[r*3+1]*t1 + GpR[r*3+2]*t2 + Gpt[r];
        }
#pragma unroll
        for (int r = 0; r < 3; ++r) {
            float rel = GR[r*3+0]*J[st+1][0] + GR[r*3+1]*J[st+1][1] + GR[r*3+2]*J[st+1][2];
            An[i*12 + r*4 + 0] = GR[r*3+0];
            An[i*12 + r*4 + 1] = GR[r*3+1];
            An[i*12 + r*4 + 2] = GR[r*3+2];
            An[i*12 + r*4 + 3] = Gt[r] - rel;
        }
#pragma unroll
        for (int r = 0; r < 9; ++r) GpR[r] = GR[r];
        Gpt[0] = Gt[0]; Gpt[1] = Gt[1]; Gpt[2] = Gt[2];
    }
}

// ---------------- K3: 8 samples x 778 verts per block; 512 threads, 2 vert-slots
// per thread. Register pressure budget: acc 48 + w 32 + temps ~25 => fits 128 VGPR
// at 4 waves/EU (16 waves/CU) with NO spill. All per-thread state is ext_vector
// SSA / macro-literal indexed.
#define GSTEP(rowptr, fk) { \
    f32x8 fv_ = *(const f32x8*)&sF[(fk)][0]; \
    const float* r0_ = (rowptr) + 3*v0; \
    const float* r1_ = (rowptr) + 3*c1; \
    float x0_=r0_[0], y0_=r0_[1], z0_=r0_[2]; \
    float x1_=r1_[0], y1_=r1_[1], z1_=r1_[2]; \
    ax0=fma8v(fv_,x0_,ax0); ay0=fma8v(fv_,y0_,ay0); az0=fma8v(fv_,z0_,az0); \
    ax1=fma8v(fv_,x1_,ax1); ay1=fma8v(fv_,y1_,ay1); az1=fma8v(fv_,z1_,az1); }

#define BLEND_I(s_, ii, j_) { \
    float vx_ = ax##ii[s_], vy_ = ay##ii[s_], vz_ = az##ii[s_]; \
    float X_ = fmaf(a0_,vx_, fmaf(a1_,vy_, fmaf(a2_,vz_, a3_))); \
    float Y_ = fmaf(a4_,vx_, fmaf(a5_,vy_, fmaf(a6_,vz_, a7_))); \
    float Z_ = fmaf(a8_,vx_, fmaf(a9_,vy_, fmaf(a10_,vz_, a11_))); \
    ox##ii = fmaf(w##ii[j_], X_, ox##ii); \
    oy##ii = fmaf(w##ii[j_], Y_, oy##ii); \
    oz##ii = fmaf(w##ii[j_], Z_, oz##ii); }

#define BLEND_J(s_, j_) { \
    const float* a_ = &sA[s_][j_][0]; \
    float a0_=a_[0], a1_=a_[1], a2_ =a_[2],  a3_ =a_[3]; \
    float a4_=a_[4], a5_=a_[5], a6_ =a_[6],  a7_ =a_[7]; \
    float a8_=a_[8], a9_=a_[9], a10_=a_[10], a11_=a_[11]; \
    BLEND_I(s_,0,j_) BLEND_I(s_,1,j_) }

#define STORE_I(s_, ii, vv) if ((vv) < NV) { \
    float* o_ = vertsA + (size_t)(n0 + s_)*M3 + (size_t)(vv)*3; \
    o_[0]=ox##ii; o_[1]=oy##ii; o_[2]=oz##ii; }

#define BLEND_S(s_) { \
    float ox0=0.f,oy0=0.f,oz0=0.f, ox1=0.f,oy1=0.f,oz1=0.f; \
    BLEND_J(s_,0)  BLEND_J(s_,1)  BLEND_J(s_,2)  BLEND_J(s_,3) \
    BLEND_J(s_,4)  BLEND_J(s_,5)  BLEND_J(s_,6)  BLEND_J(s_,7) \
    BLEND_J(s_,8)  BLEND_J(s_,9)  BLEND_J(s_,10) BLEND_J(s_,11) \
    BLEND_J(s_,12) BLEND_J(s_,13) BLEND_J(s_,14) BLEND_J(s_,15) \
    STORE_I(s_,0,v0) STORE_I(s_,1,v1) }

__global__ __launch_bounds__(512, 4) void k3_verts(
    const float* __restrict__ beta,
    const float* __restrict__ posedirs,
    const float* __restrict__ shapedirs,
    const float* __restrict__ vtemp,
    const float* __restrict__ weights,
    const float* __restrict__ Rs,
    float* vertsA,                      // reads A stash, writes verts (same region)
    int N)
{
    __shared__ __attribute__((aligned(32))) float sF[145][S]; // 10 beta + 135 posefeat
    __shared__ __attribute__((aligned(16))) float sA[S][NJ][12];
    const int n0  = blockIdx.x * S;
    const int tid = threadIdx.x;

    // stage features: k<10 -> beta[k]; k>=10 -> Rs[9 + (k-10)] - I
    for (int idx = tid; idx < 145 * S; idx += 512) {
        int k = idx / S, s = idx % S;
        float val;
        if (k < 10) {
            val = beta[(size_t)(n0+s)*10 + k];
        } else {
            int kk = k - 10;
            int rr = kk % 9;
            val = Rs[(size_t)(n0+s)*144 + 9 + kk];
            if ((rr & 3) == 0) val -= 1.f;   // rr in {0,4,8}
        }
        sF[k][s] = val;
    }
    // stage A (16 joints x 12) per sample from the verts-region stash
    for (int idx = tid; idx < S * 192; idx += 512) {
        int s = idx / 192, r = idx % 192;
        (&sA[0][0][0])[idx] = vertsA[(size_t)(n0+s)*M3 + r];
    }
    __syncthreads();

    const int v0 = tid;               // 0..511, always < NV
    const int v1 = tid + 512;         // 512..1023
    const int c1 = (v1 < NV) ? v1 : (NV - 1);   // clamp: no divergent compute

    // accumulators: 6 named f32x8 (xyz for 2 vert-slots, vector over 8 samples)
    f32x8 ax0 = splat8(vtemp[v0*3+0]), ay0 = splat8(vtemp[v0*3+1]), az0 = splat8(vtemp[v0*3+2]);
    f32x8 ax1 = splat8(vtemp[c1*3+0]), ay1 = splat8(vtemp[c1*3+1]), az1 = splat8(vtemp[c1*3+2]);

    // GEMM: v_shaped + v_posed accumulation
    for (int k = 0; k < 10; ++k)  { GSTEP(shapedirs + (size_t)k*M3, k) }
    for (int k = 0; k < 135; ++k) { GSTEP(posedirs  + (size_t)k*M3, k + 10) }

    // skinning weights: 2 named f32x16 (constant-index access only)
    f32x16 w0 = *(const f32x16*)&weights[(size_t)v0*16];
    f32x16 w1 = *(const f32x16*)&weights[(size_t)c1*16];

    // LBS blend + store, fully macro-expanded
    BLEND_S(0) BLEND_S(1) BLEND_S(2) BLEND_S(3)
    BLEND_S(4) BLEND_S(5) BLEND_S(6) BLEND_S(7)
}

// ---------------- K4: joints = einsum('nvc,vj->njc', verts, Jreg). Block per sample.
__global__ __launch_bounds__(256) void k4_joints(
    const float* __restrict__ verts,
    const float* __restrict__ Jreg,
    float* __restrict__ joints,
    int N)
{
    int n = blockIdx.x;
    int tid = threadIdx.x;
    float ja[48];
#pragma unroll
    for (int r = 0; r < 48; ++r) ja[r] = 0.f;
    for (int v = tid; v < NV; v += 256) {
        float x = verts[(size_t)n*M3 + v*3 + 0];
        float y = verts[(size_t)n*M3 + v*3 + 1];
        float z = verts[(size_t)n*M3 + v*3 + 2];
        const float4* jr = reinterpret_cast<const float4*>(Jreg + (size_t)v * 16);
#pragma unroll
        for (int q = 0; q < 4; ++q) {
            float4 t = jr[q];
            ja[(q*4+0)*3+0] = fmaf(t.x, x, ja[(q*4+0)*3+0]);
            ja[(q*4+0)*3+1] = fmaf(t.x, y, ja[(q*4+0)*3+1]);
            ja[(q*4+0)*3+2] = fmaf(t.x, z, ja[(q*4+0)*3+2]);
            ja[(q*4+1)*3+0] = fmaf(t.y, x, ja[(q*4+1)*3+0]);
            ja[(q*4+1)*3+1] = fmaf(t.y, y, ja[(q*4+1)*3+1]);
            ja[(q*4+1)*3+2] = fmaf(t.y, z, ja[(q*4+1)*3+2]);
            ja[(q*4+2)*3+0] = fmaf(t.z, x, ja[(q*4+2)*3+0]);
            ja[(q*4+2)*3+1] = fmaf(t.z, y, ja[(q*4+2)*3+1]);
            ja[(q*4+2)*3+2] = fmaf(t.z, z, ja[(q*4+2)*3+2]);
            ja[(q*4+3)*3+0] = fmaf(t.w, x, ja[(q*4+3)*3+0]);
            ja[(q*4+3)*3+1] = fmaf(t.w, y, ja[(q*4+3)*3+1]);
            ja[(q*4+3)*3+2] = fmaf(t.w, z, ja[(q*4+3)*3+2]);
        }
    }
#pragma unroll
    for (int m = 1; m < 64; m <<= 1) {
#pragma unroll
        for (int r = 0; r < 48; ++r) ja[r] += __shfl_xor(ja[r], m);
    }
    __shared__ float red[4][48];
    int wave = tid >> 6;
    if ((tid & 63) == 0) {
#pragma unroll
        for (int r = 0; r < 48; ++r) red[wave][r] = ja[r];
    }
    __syncthreads();
    if (tid < 48)
        joints[(size_t)n*48 + tid] = red[0][tid] + red[1][tid] + red[2][tid] + red[3][tid];
}

extern "C" void kernel_launch(void* const* d_in, const int* in_sizes, int n_in,
                              void* d_out, int out_size, void* d_ws, size_t ws_size,
                              hipStream_t stream)
{
    const float* beta   = (const float*)d_in[0];
    const float* theta  = (const float*)d_in[1];
    const float* vtemp  = (const float*)d_in[2];
    const float* shaped = (const float*)d_in[3];
    const float* Jreg   = (const float*)d_in[4];
    const float* posed  = (const float*)d_in[5];
    const float* wts    = (const float*)d_in[6];
    float* out = (float*)d_out;
    const int N = in_sizes[0] / 10;   // 4096

    float* verts  = out;                            // N*2334
    float* joints = out + (size_t)N * M3;           // N*48
    float* RsOut  = joints + (size_t)N * 48;        // N*144

    k0_prep<<<176, 64, 0, stream>>>(shaped, Jreg, vtemp, joints);
    k1_rodrigues<<<(N*NJ + 255)/256, 256, 0, stream>>>(theta, RsOut, N);
    k2_chain<<<(N*5 + 63)/64, 64, 0, stream>>>(beta, RsOut, joints, verts, N);
    k3_verts<<<N/S, 512, 0, stream>>>(beta, posed, shaped, vtemp, wts, RsOut, verts, N);
    k4_joints<<<N, 256, 0, stream>>>(verts, Jreg, joints, N);
}

// Round 5
// 169.084 us; speedup vs baseline: 5.4681x; 5.4681x over previous
//
#include <hip/hip_runtime.h>
#include <math.h>

#define NJ 16
#define NV 778
#define M3 2334   // NV*3
#define S  8      // samples per block in k3a

typedef float f32x8  __attribute__((ext_vector_type(8)));
typedef float f32x16 __attribute__((ext_vector_type(16)));

__device__ __forceinline__ f32x8 splat8(float x) {
    f32x8 r = {x, x, x, x, x, x, x, x};
    return r;
}
// elementwise fused r = f*s + c  (all constant indices -> pure SSA)
__device__ __forceinline__ f32x8 fma8v(f32x8 f, float s, f32x8 c) {
    f32x8 r;
    r[0] = fmaf(f[0], s, c[0]); r[1] = fmaf(f[1], s, c[1]);
    r[2] = fmaf(f[2], s, c[2]); r[3] = fmaf(f[3], s, c[3]);
    r[4] = fmaf(f[4], s, c[4]); r[5] = fmaf(f[5], s, c[5]);
    r[6] = fmaf(f[6], s, c[6]); r[7] = fmaf(f[7], s, c[7]);
    return r;
}

// d_out layout (floats): verts [N*2334] | joints [N*48] | Rs [N*144]
// Stashes:
//   SJ/JT (528 floats) -> joints region (overwritten by k4 at the end)
//   A (N x 16 x 12)    -> d_ws (N*192 floats = 3.1 MB)
// Pipeline: k0 -> k1 -> k2(A->ws) -> k3a(v_posed->verts) -> k3b(in-place LBS) -> k4

// ---------------- K0: SJ[b,j,c] = sum_v shapedirs[b,v,c]*Jreg[v,j]; b==10 -> vtemp
__global__ __launch_bounds__(64) void k0_prep(
    const float* __restrict__ shapedirs,
    const float* __restrict__ Jreg,
    const float* __restrict__ vtemp,
    float* __restrict__ SJJT)   // 528 floats
{
    int b = blockIdx.x / 16;    // 0..9 = shapedirs row, 10 = vtemp
    int j = blockIdx.x % 16;
    int t = threadIdx.x;
    const float* src = (b < 10) ? (shapedirs + (size_t)b * M3) : vtemp;
    float a0 = 0.f, a1 = 0.f, a2 = 0.f;
    for (int v = t; v < NV; v += 64) {
        float jr = Jreg[v * 16 + j];
        a0 = fmaf(src[v*3 + 0], jr, a0);
        a1 = fmaf(src[v*3 + 1], jr, a1);
        a2 = fmaf(src[v*3 + 2], jr, a2);
    }
#pragma unroll
    for (int m = 1; m < 64; m <<= 1) {
        a0 += __shfl_xor(a0, m);
        a1 += __shfl_xor(a1, m);
        a2 += __shfl_xor(a2, m);
    }
    if (t == 0) {
        int base = (b < 10) ? (b*48 + j*3) : (480 + j*3);
        SJJT[base + 0] = a0;
        SJJT[base + 1] = a1;
        SJJT[base + 2] = a2;
    }
}

// ---------------- K1: Rodrigues, one thread per (n, joint)
__global__ __launch_bounds__(256) void k1_rodrigues(
    const float* __restrict__ theta, float* __restrict__ RsOut, int N)
{
    int idx = blockIdx.x * 256 + threadIdx.x;
    if (idx >= N * NJ) return;
    int n = idx >> 4;
    int j = idx & 15;
    float t0 = theta[n*48 + j*3 + 0];
    float t1 = theta[n*48 + j*3 + 1];
    float t2 = theta[n*48 + j*3 + 2];
    const float eps = 1e-8f;
    float a0 = t0 + eps, a1 = t1 + eps, a2 = t2 + eps;
    float angle = sqrtf(a0*a0 + a1*a1 + a2*a2);
    float inv  = 1.0f / angle;
    float half = 0.5f * angle;
    float sh = sinf(half), chh = cosf(half);
    float qw = chh;
    float qx = sh * t0 * inv;
    float qy = sh * t1 * inv;
    float qz = sh * t2 * inv;
    float qn = 1.0f / sqrtf(qw*qw + qx*qx + qy*qy + qz*qz);
    qw *= qn; qx *= qn; qy *= qn; qz *= qn;
    float w2=qw*qw, x2=qx*qx, y2=qy*qy, z2=qz*qz;
    float wx=qw*qx, wy=qw*qy, wz=qw*qz;
    float xy=qx*qy, xz=qx*qz, yz=qy*qz;
    float* R = RsOut + (size_t)idx * 9;
    R[0] = w2 + x2 - y2 - z2;
    R[1] = 2.f*(xy - wz);
    R[2] = 2.f*(wy + xz);
    R[3] = 2.f*(wz + xy);
    R[4] = w2 - x2 + y2 - z2;
    R[5] = 2.f*(yz - wx);
    R[6] = 2.f*(xz - wy);
    R[7] = 2.f*(wx + yz);
    R[8] = w2 - x2 - y2 + z2;
}

// ---------------- K2: kinematic chain -> A into d_ws (192 floats / sample)
__global__ __launch_bounds__(64) void k2_chain(
    const float* __restrict__ beta,
    const float* __restrict__ Rs,     // d_out Rs region
    const float* __restrict__ SJJT,   // 528 floats
    float* __restrict__ Aws,          // d_ws; A[n] at n*192
    int N)
{
    __shared__ float sS[528];
    for (int i = threadIdx.x; i < 528; i += 64) sS[i] = SJJT[i];
    __syncthreads();
    int gid = blockIdx.x * 64 + threadIdx.x;
    if (gid >= N * 5) return;
    int n  = gid / 5;
    int ch = gid % 5;

    float b[10];
#pragma unroll
    for (int i = 0; i < 10; ++i) b[i] = beta[n*10 + i];

    int jidx[4];
    jidx[0] = 0; jidx[1] = ch*3 + 1; jidx[2] = ch*3 + 2; jidx[3] = ch*3 + 3;
    float J[4][3];
#pragma unroll
    for (int q = 0; q < 4; ++q) {
        int j = jidx[q];
#pragma unroll
        for (int c = 0; c < 3; ++c) {
            float acc = sS[480 + j*3 + c];
#pragma unroll
            for (int qq = 0; qq < 10; ++qq)
                acc = fmaf(b[qq], sS[qq*48 + j*3 + c], acc);
            J[q][c] = acc;
        }
    }

    const float* Rn = Rs + (size_t)n * 144;
    float* An = Aws + (size_t)n * 192;

    float GpR[9], Gpt[3];
#pragma unroll
    for (int r = 0; r < 3; ++r) {
        GpR[r*3+0] =  Rn[r*3+0];
        GpR[r*3+1] = -Rn[r*3+1];
        GpR[r*3+2] = -Rn[r*3+2];
    }
    Gpt[0] = J[0][0]; Gpt[1] = J[0][1]; Gpt[2] = J[0][2];

    if (ch == 0) {
#pragma unroll
        for (int r = 0; r < 3; ++r) {
            float rel = GpR[r*3+0]*J[0][0] + GpR[r*3+1]*J[0][1] + GpR[r*3+2]*J[0][2];
            An[r*4 + 0] = GpR[r*3+0];
            An[r*4 + 1] = GpR[r*3+1];
            An[r*4 + 2] = GpR[r*3+2];
            An[r*4 + 3] = Gpt[r] - rel;
        }
    }

#pragma unroll
    for (int st = 0; st < 3; ++st) {
        int i = jidx[st+1];
        const float* Ri = Rn + (size_t)i * 9;
        float t0 = J[st+1][0] - J[st][0];
        float t1 = J[st+1][1] - J[st][1];
        float t2 = J[st+1][2] - J[st][2];
        float GR[9], Gt[3];
#pragma unroll
        for (int r = 0; r < 3; ++r) {
#pragma unroll
            for (int c = 0; c < 3; ++c)
                GR[r*3+c] = GpR[r*3+0]*Ri[c] + GpR[r*3+1]*Ri[3+c] + GpR[r*3+2]*Ri[6+c];
            Gt[r] = GpR[r*3+0]*t0 + GpR[r*3+1]*t1 + GpR[r*3+2]*t2 + Gpt[r];
        }
#pragma unroll
        for (int r = 0; r < 3; ++r) {
            float rel = GR[r*3+0]*J[st+1][0] + GR[r*3+1]*J[st+1][1] + GR[r*3+2]*J[st+1][2];
            An[i*12 + r*4 + 0] = GR[r*3+0];
            An[i*12 + r*4 + 1] = GR[r*3+1];
            An[i*12 + r*4 + 2] = GR[r*3+2];
            An[i*12 + r*4 + 3] = Gt[r] - rel;
        }
#pragma unroll
        for (int r = 0; r < 9; ++r) GpR[r] = GR[r];
        Gpt[0] = Gt[0]; Gpt[1] = Gt[1]; Gpt[2] = Gt[2];
    }
}

// ---------------- K3a: GEMM only. 8 samples x 778 verts per block; 256 threads,
// 4 vert-slots/thread. acc = 12 f32x8 = 96 VGPR + temps; launch_bounds(256,1)
// leaves the allocator a ~512-VGPR cap -> no spill at low occupancy; ILP-8 hides
// latency. Writes v_posed to verts region.
#define GSTEP(rowptr, fk) { \
    f32x8 fv_ = *(const f32x8*)&sF[(fk)][0]; \
    const float* r0_ = (rowptr) + 3*v0; \
    const float* r1_ = (rowptr) + 3*v1; \
    const float* r2_ = (rowptr) + 3*v2; \
    const float* r3_ = (rowptr) + 3*c3; \
    float x0_=r0_[0], y0_=r0_[1], z0_=r0_[2]; \
    float x1_=r1_[0], y1_=r1_[1], z1_=r1_[2]; \
    float x2_=r2_[0], y2_=r2_[1], z2_=r2_[2]; \
    float x3_=r3_[0], y3_=r3_[1], z3_=r3_[2]; \
    ax0=fma8v(fv_,x0_,ax0); ay0=fma8v(fv_,y0_,ay0); az0=fma8v(fv_,z0_,az0); \
    ax1=fma8v(fv_,x1_,ax1); ay1=fma8v(fv_,y1_,ay1); az1=fma8v(fv_,z1_,az1); \
    ax2=fma8v(fv_,x2_,ax2); ay2=fma8v(fv_,y2_,ay2); az2=fma8v(fv_,z2_,az2); \
    ax3=fma8v(fv_,x3_,ax3); ay3=fma8v(fv_,y3_,ay3); az3=fma8v(fv_,z3_,az3); }

#define STORE_SLOT(s_, ii, vv) if ((vv) < NV) { \
    float* o_ = vposed + (size_t)(n0 + s_)*M3 + (size_t)(vv)*3; \
    o_[0] = ax##ii[s_]; o_[1] = ay##ii[s_]; o_[2] = az##ii[s_]; }

#define STORE_S(s_) { \
    STORE_SLOT(s_,0,v0) STORE_SLOT(s_,1,v1) STORE_SLOT(s_,2,v2) STORE_SLOT(s_,3,v3) }

__global__ __launch_bounds__(256, 1) void k3a_gemm(
    const float* __restrict__ beta,
    const float* __restrict__ posedirs,
    const float* __restrict__ shapedirs,
    const float* __restrict__ vtemp,
    const float* __restrict__ Rs,
    float* __restrict__ vposed,         // verts region
    int N)
{
    __shared__ __attribute__((aligned(32))) float sF[145][S]; // 10 beta + 135 posefeat
    const int n0  = blockIdx.x * S;
    const int tid = threadIdx.x;

    // stage features: k<10 -> beta[k]; k>=10 -> Rs[9 + (k-10)] - I
    for (int idx = tid; idx < 145 * S; idx += 256) {
        int k = idx / S, s = idx % S;
        float val;
        if (k < 10) {
            val = beta[(size_t)(n0+s)*10 + k];
        } else {
            int kk = k - 10;
            int rr = kk % 9;
            val = Rs[(size_t)(n0+s)*144 + 9 + kk];
            if ((rr & 3) == 0) val -= 1.f;   // rr in {0,4,8}
        }
        sF[k][s] = val;
    }
    __syncthreads();

    const int v0 = tid, v1 = tid + 256, v2 = tid + 512, v3 = tid + 768;
    const int c3 = (v3 < NV) ? v3 : (NV - 1);   // clamp: no divergent compute

    f32x8 ax0 = splat8(vtemp[v0*3+0]), ay0 = splat8(vtemp[v0*3+1]), az0 = splat8(vtemp[v0*3+2]);
    f32x8 ax1 = splat8(vtemp[v1*3+0]), ay1 = splat8(vtemp[v1*3+1]), az1 = splat8(vtemp[v1*3+2]);
    f32x8 ax2 = splat8(vtemp[v2*3+0]), ay2 = splat8(vtemp[v2*3+1]), az2 = splat8(vtemp[v2*3+2]);
    f32x8 ax3 = splat8(vtemp[c3*3+0]), ay3 = splat8(vtemp[c3*3+1]), az3 = splat8(vtemp[c3*3+2]);

    for (int k = 0; k < 10; ++k)  { GSTEP(shapedirs + (size_t)k*M3, k) }
    for (int k = 0; k < 135; ++k) { GSTEP(posedirs  + (size_t)k*M3, k + 10) }

    STORE_S(0) STORE_S(1) STORE_S(2) STORE_S(3)
    STORE_S(4) STORE_S(5) STORE_S(6) STORE_S(7)
}

// ---------------- K3b: LBS blend, in place. Block = (sample, vert-quarter).
// A staged in LDS as 48 float4 rows (broadcast reads); w one f32x16/thread.
#define BJ(j_) { \
    float4 A0 = sA4[(j_)*3+0], A1 = sA4[(j_)*3+1], A2 = sA4[(j_)*3+2]; \
    float X_ = fmaf(A0.x,vx, fmaf(A0.y,vy, fmaf(A0.z,vz, A0.w))); \
    float Y_ = fmaf(A1.x,vx, fmaf(A1.y,vy, fmaf(A1.z,vz, A1.w))); \
    float Z_ = fmaf(A2.x,vx, fmaf(A2.y,vy, fmaf(A2.z,vz, A2.w))); \
    ox = fmaf(w[j_], X_, ox); \
    oy = fmaf(w[j_], Y_, oy); \
    oz = fmaf(w[j_], Z_, oz); }

__global__ __launch_bounds__(256, 4) void k3b_blend(
    const float* __restrict__ Aws,      // d_ws
    const float* __restrict__ weights,
    float* verts,                       // in-place: reads v_posed, writes verts
    int N)
{
    __shared__ __attribute__((aligned(16))) float4 sA4[48];
    const int n   = blockIdx.x;
    const int tid = threadIdx.x;
    if (tid < 48) sA4[tid] = reinterpret_cast<const float4*>(Aws + (size_t)n * 192)[tid];
    __syncthreads();

    const int v = blockIdx.y * 256 + tid;
    if (v >= NV) return;

    float* vp = verts + (size_t)n * M3 + (size_t)v * 3;
    float vx = vp[0], vy = vp[1], vz = vp[2];
    f32x16 w = *reinterpret_cast<const f32x16*>(&weights[(size_t)v * 16]);
    float ox = 0.f, oy = 0.f, oz = 0.f;

    BJ(0)  BJ(1)  BJ(2)  BJ(3)  BJ(4)  BJ(5)  BJ(6)  BJ(7)
    BJ(8)  BJ(9)  BJ(10) BJ(11) BJ(12) BJ(13) BJ(14) BJ(15)

    vp[0] = ox; vp[1] = oy; vp[2] = oz;
}

// ---------------- K4: joints = einsum('nvc,vj->njc', verts, Jreg). Block per sample.
__global__ __launch_bounds__(256) void k4_joints(
    const float* __restrict__ verts,
    const float* __restrict__ Jreg,
    float* __restrict__ joints,
    int N)
{
    int n = blockIdx.x;
    int tid = threadIdx.x;
    float ja[48];
#pragma unroll
    for (int r = 0; r < 48; ++r) ja[r] = 0.f;
    for (int v = tid; v < NV; v += 256) {
        float x = verts[(size_t)n*M3 + v*3 + 0];
        float y = verts[(size_t)n*M3 + v*3 + 1];
        float z = verts[(size_t)n*M3 + v*3 + 2];
        const float4* jr = reinterpret_cast<const float4*>(Jreg + (size_t)v * 16);
#pragma unroll
        for (int q = 0; q < 4; ++q) {
            float4 t = jr[q];
            ja[(q*4+0)*3+0] = fmaf(t.x, x, ja[(q*4+0)*3+0]);
            ja[(q*4+0)*3+1] = fmaf(t.x, y, ja[(q*4+0)*3+1]);
            ja[(q*4+0)*3+2] = fmaf(t.x, z, ja[(q*4+0)*3+2]);
            ja[(q*4+1)*3+0] = fmaf(t.y, x, ja[(q*4+1)*3+0]);
            ja[(q*4+1)*3+1] = fmaf(t.y, y, ja[(q*4+1)*3+1]);
            ja[(q*4+1)*3+2] = fmaf(t.y, z, ja[(q*4+1)*3+2]);
            ja[(q*4+2)*3+0] = fmaf(t.z, x, ja[(q*4+2)*3+0]);
            ja[(q*4+2)*3+1] = fmaf(t.z, y, ja[(q*4+2)*3+1]);
            ja[(q*4+2)*3+2] = fmaf(t.z, z, ja[(q*4+2)*3+2]);
            ja[(q*4+3)*3+0] = fmaf(t.w, x, ja[(q*4+3)*3+0]);
            ja[(q*4+3)*3+1] = fmaf(t.w, y, ja[(q*4+3)*3+1]);
            ja[(q*4+3)*3+2] = fmaf(t.w, z, ja[(q*4+3)*3+2]);
        }
    }
#pragma unroll
    for (int m = 1; m < 64; m <<= 1) {
#pragma unroll
        for (int r = 0; r < 48; ++r) ja[r] += __shfl_xor(ja[r], m);
    }
    __shared__ float red[4][48];
    int wave = tid >> 6;
    if ((tid & 63) == 0) {
#pragma unroll
        for (int r = 0; r < 48; ++r) red[wave][r] = ja[r];
    }
    __syncthreads();
    if (tid < 48)
        joints[(size_t)n*48 + tid] = red[0][tid] + red[1][tid] + red[2][tid] + red[3][tid];
}

extern "C" void kernel_launch(void* const* d_in, const int* in_sizes, int n_in,
                              void* d_out, int out_size, void* d_ws, size_t ws_size,
                              hipStream_t stream)
{
    const float* beta   = (const float*)d_in[0];
    const float* theta  = (const float*)d_in[1];
    const float* vtemp  = (const float*)d_in[2];
    const float* shaped = (const float*)d_in[3];
    const float* Jreg   = (const float*)d_in[4];
    const float* posed  = (const float*)d_in[5];
    const float* wts    = (const float*)d_in[6];
    float* out = (float*)d_out;
    const int N = in_sizes[0] / 10;   // 4096

    float* verts  = out;                            // N*2334
    float* joints = out + (size_t)N * M3;           // N*48
    float* RsOut  = joints + (size_t)N * 48;        // N*144
    float* Aws    = (float*)d_ws;                   // N*192 floats = 3.1 MB

    k0_prep<<<176, 64, 0, stream>>>(shaped, Jreg, vtemp, joints);
    k1_rodrigues<<<(N*NJ + 255)/256, 256, 0, stream>>>(theta, RsOut, N);
    k2_chain<<<(N*5 + 63)/64, 64, 0, stream>>>(beta, RsOut, joints, Aws, N);
    k3a_gemm<<<N/S, 256, 0, stream>>>(beta, posed, shaped, vtemp, RsOut, verts, N);
    k3b_blend<<<dim3(N, 4), 256, 0, stream>>>(Aws, wts, verts, N);
    k4_joints<<<N, 256, 0, stream>>>(verts, Jreg, joints, N);
}